// Round 6
// baseline (320.972 us; speedup 1.0000x reference)
//
#include <hip/hip_runtime.h>
#include <stdint.h>

#define DM 1024
#define HD 64
#define NH 16
#define SEQ 2048
#define NB 4

typedef __bf16 bf16x8 __attribute__((ext_vector_type(8)));
typedef float f32x4 __attribute__((ext_vector_type(4)));

__device__ __forceinline__ float bf2f(uint16_t b) {
    uint32_t u = ((uint32_t)b) << 16;
    float f;
    __builtin_memcpy(&f, &u, 4);
    return f;
}
__device__ __forceinline__ uint16_t f2bf(float f) {
    uint32_t u;
    __builtin_memcpy(&u, &f, 4);
    u += 0x7fffu + ((u >> 16) & 1u);   // RNE
    return (uint16_t)(u >> 16);
}

__device__ __forceinline__ void gll16(const void* g, void* l) {
    __builtin_amdgcn_global_load_lds(
        (const __attribute__((address_space(1))) void*)g,
        (__attribute__((address_space(3))) void*)l, 16, 0, 0);
}

// ---------------------------------------------------------------------------
// f32 -> bf16 convert, 8 elems/thread (two float4 loads, one 16B store)
// ---------------------------------------------------------------------------
__global__ __launch_bounds__(256) void cvt_f32_bf16(const float* __restrict__ in,
                                                    uint16_t* __restrict__ out) {
    const size_t i = (size_t)blockIdx.x * 256 + threadIdx.x;
    const float4* p = (const float4*)in + i * 2;
    const float4 a = p[0], b = p[1];
    uint16_t o[8] = {f2bf(a.x), f2bf(a.y), f2bf(a.z), f2bf(a.w),
                     f2bf(b.x), f2bf(b.y), f2bf(b.z), f2bf(b.w)};
    __builtin_memcpy(out + i * 8, o, 16);
}

// ---------------------------------------------------------------------------
// Weight transpose + convert: out[C][R] (bf16) = in[R][C] (f32)
// ---------------------------------------------------------------------------
__global__ void transpose_cvt(const float* __restrict__ in,
                              uint16_t* __restrict__ out, int R, int C) {
    __shared__ uint16_t t[32][33];
    const int bx = blockIdx.x * 32, by = blockIdx.y * 32;
    const int tx = threadIdx.x, ty = threadIdx.y;
#pragma unroll
    for (int i = ty; i < 32; i += 8)
        t[i][tx] = f2bf(in[(size_t)(by + i) * C + bx + tx]);
    __syncthreads();
#pragma unroll
    for (int i = ty; i < 32; i += 8)
        out[(size_t)(bx + i) * R + by + tx] = t[tx][i];
}

// ---------------------------------------------------------------------------
// bf16 transpose (for V): out[C][R] = in[R][C], batched over blockIdx.z
// ---------------------------------------------------------------------------
__global__ void transpose_bf16(const uint16_t* __restrict__ in,
                               uint16_t* __restrict__ out, int R, int C) {
    __shared__ uint16_t t[32][33];
    const int bx = blockIdx.x * 32, by = blockIdx.y * 32;
    const size_t zo = (size_t)blockIdx.z * R * C;
    in += zo; out += zo;
    const int tx = threadIdx.x, ty = threadIdx.y;
#pragma unroll
    for (int i = ty; i < 32; i += 8)
        t[i][tx] = in[(size_t)(by + i) * C + bx + tx];
    __syncthreads();
#pragma unroll
    for (int i = ty; i < 32; i += 8)
        out[(size_t)(bx + i) * R + by + tx] = t[tx][i];
}

// ---------------------------------------------------------------------------
// bf16 GEMM: C[M][N] = A[M][K] @ Bt[N][K]^T   (Bt is pre-transposed weight)
// 128x128 tile, BK=64, 256 threads (4 waves, 2x2), mfma_f32_16x16x32_bf16.
// XOR swizzle ((row&7)<<4) applied on stage-source and ds_read.
// OT = uint16_t (bf16 store) or float (f32 store, for the final GEMM).
// ---------------------------------------------------------------------------
template <typename OT>
__global__ __launch_bounds__(256) void gemm_bf16(
    const uint16_t* __restrict__ A, const uint16_t* __restrict__ Bt,
    OT* __restrict__ C, int M, int N, int K) {
    __shared__ uint16_t As[128 * 64];
    __shared__ uint16_t Bs[128 * 64];
    const int tid = threadIdx.x;
    const int wave = tid >> 6, lane = tid & 63;
    const int g = lane >> 4, l15 = lane & 15;
    const int m0 = blockIdx.y * 128, n0 = blockIdx.x * 128;
    const int wr = wave >> 1, wc = wave & 1;

    f32x4 acc[4][4];
    const f32x4 z4 = {0.f, 0.f, 0.f, 0.f};
#pragma unroll
    for (int i = 0; i < 4; i++)
#pragma unroll
        for (int j = 0; j < 4; j++) acc[i][j] = z4;

    for (int k0 = 0; k0 < K; k0 += 64) {
        __syncthreads();
#pragma unroll
        for (int i = 0; i < 4; i++) {
            const int c = wave * 4 + i;
            const int o = (c * 64 + lane) * 16;
            const int row = o >> 7, off = o & 127;
            const int soff = off ^ ((row & 7) << 4);
            gll16((const char*)A + (((size_t)(m0 + row) * K + k0) << 1) + soff,
                  (char*)As + c * 1024);
            gll16((const char*)Bt + (((size_t)(n0 + row) * K + k0) << 1) + soff,
                  (char*)Bs + c * 1024);
        }
        __syncthreads();
#pragma unroll
        for (int ks = 0; ks < 2; ks++) {
            bf16x8 a[4], b[4];
#pragma unroll
            for (int mi = 0; mi < 4; mi++) {
                const int row = wr * 64 + mi * 16 + l15;
                a[mi] = *(const bf16x8*)((const char*)As + row * 128 +
                                         ((ks * 64 + g * 16) ^ ((row & 7) << 4)));
            }
#pragma unroll
            for (int ni = 0; ni < 4; ni++) {
                const int row = wc * 64 + ni * 16 + l15;
                b[ni] = *(const bf16x8*)((const char*)Bs + row * 128 +
                                         ((ks * 64 + g * 16) ^ ((row & 7) << 4)));
            }
#pragma unroll
            for (int mi = 0; mi < 4; mi++)
#pragma unroll
                for (int ni = 0; ni < 4; ni++)
                    acc[mi][ni] = __builtin_amdgcn_mfma_f32_16x16x32_bf16(
                        a[mi], b[ni], acc[mi][ni], 0, 0, 0);
        }
    }
#pragma unroll
    for (int mi = 0; mi < 4; mi++)
#pragma unroll
        for (int ni = 0; ni < 4; ni++) {
            const int row = m0 + wr * 64 + mi * 16 + g * 4;
            const int col = n0 + wc * 64 + ni * 16 + l15;
#pragma unroll
            for (int r = 0; r < 4; r++) {
                if constexpr (sizeof(OT) == 4)
                    C[(size_t)(row + r) * N + col] = acc[mi][ni][r];
                else
                    C[(size_t)(row + r) * N + col] = f2bf(acc[mi][ni][r]);
            }
        }
}

// ---------------------------------------------------------------------------
// Flash attention fwd. Swapped QK^T: S^T = mfma(A=K, B=Q^T) so the softmax
// reduction is lane-local + 2 shuffles. P via per-wave swizzled LDS; V is
// pre-transposed globally (Vt[b][dglob][s]) so PV B-frags are key-contiguous.
// Block: 256 thr = 4 waves; 32 q-rows/wave (128/block); KV tile = 64.
// Q pre-scaled by 1/sqrt(D_K)=0.125 at load.
// ---------------------------------------------------------------------------
__global__ __launch_bounds__(256) void attn_fwd(
    const uint16_t* __restrict__ Q, const uint16_t* __restrict__ Kb,
    const uint16_t* __restrict__ Vt, uint16_t* __restrict__ AO) {
    __shared__ uint16_t Ks[64 * 64];       // [key][d]   swizzled
    __shared__ uint16_t Vs[64 * 64];       // [d][key]   swizzled
    __shared__ uint16_t Pt[4][32 * 64];    // per-wave [q][key] swizzled
    const int tid = threadIdx.x;
    const int wave = tid >> 6, lane = tid & 63;
    const int g = lane >> 4, l15 = lane & 15;
    const int qt = blockIdx.x, h = blockIdx.y, b = blockIdx.z;
    const int q0 = qt * 128 + wave * 32;   // seq-local

    // Q fragments (B-operand for S^T), scaled by 0.125
    bf16x8 qf[2][2];
#pragma unroll
    for (int qi = 0; qi < 2; qi++)
#pragma unroll
        for (int ks = 0; ks < 2; ks++) {
            const uint16_t* src = Q + (size_t)(b * SEQ + q0 + qi * 16 + l15) * DM +
                                  h * HD + ks * 32 + g * 8;
            uint16_t tmp[8], ov[8];
            __builtin_memcpy(tmp, src, 16);
#pragma unroll
            for (int j = 0; j < 8; j++) ov[j] = f2bf(bf2f(tmp[j]) * 0.125f);
            __builtin_memcpy(&qf[qi][ks], ov, 16);
        }

    f32x4 accO[2][4];
    const f32x4 z4 = {0.f, 0.f, 0.f, 0.f};
#pragma unroll
    for (int i = 0; i < 2; i++)
#pragma unroll
        for (int j = 0; j < 4; j++) accO[i][j] = z4;
    float m_run[2] = {-1e30f, -1e30f};
    float l_run[2] = {0.f, 0.f};

    for (int kt = 0; kt < SEQ / 64; kt++) {
        __syncthreads();   // previous tile's LDS reads done
#pragma unroll
        for (int i = 0; i < 2; i++) {
            const int c = wave * 2 + i;
            const int o = (c * 64 + lane) * 16;
            const int row = o >> 7, off = o & 127;
            const int soff = off ^ ((row & 7) << 4);
            gll16((const char*)Kb +
                      (((size_t)(b * SEQ + kt * 64 + row) * DM + h * HD) << 1) + soff,
                  (char*)Ks + c * 1024);
            gll16((const char*)Vt +
                      (((size_t)(b * DM + h * HD + row) * SEQ + kt * 64) << 1) + soff,
                  (char*)Vs + c * 1024);
        }
        __syncthreads();   // staging visible

        // S^T = K . Q^T : frags sf[kf][qi]; lane holds q=l15(+16qi), key=g*4+r(+16kf)
        f32x4 sf[4][2];
#pragma unroll
        for (int kf = 0; kf < 4; kf++)
#pragma unroll
            for (int qi = 0; qi < 2; qi++) sf[kf][qi] = z4;
#pragma unroll
        for (int ks = 0; ks < 2; ks++)
#pragma unroll
            for (int kf = 0; kf < 4; kf++) {
                const int row = kf * 16 + l15;
                bf16x8 a = *(const bf16x8*)((const char*)Ks + row * 128 +
                                            ((ks * 64 + g * 16) ^ ((row & 7) << 4)));
#pragma unroll
                for (int qi = 0; qi < 2; qi++)
                    sf[kf][qi] = __builtin_amdgcn_mfma_f32_16x16x32_bf16(
                        a, qf[qi][ks], sf[kf][qi], 0, 0, 0);
            }

        // online softmax per q-column
        float corr[2];
#pragma unroll
        for (int qi = 0; qi < 2; qi++) {
            float mx = -1e30f;
#pragma unroll
            for (int kf = 0; kf < 4; kf++)
#pragma unroll
                for (int r = 0; r < 4; r++) mx = fmaxf(mx, sf[kf][qi][r]);
            mx = fmaxf(mx, __shfl_xor(mx, 16));
            mx = fmaxf(mx, __shfl_xor(mx, 32));
            const float mnew = fmaxf(m_run[qi], mx);
            corr[qi] = __expf(m_run[qi] - mnew);
            m_run[qi] = mnew;
            float ls = 0.f;
#pragma unroll
            for (int kf = 0; kf < 4; kf++)
#pragma unroll
                for (int r = 0; r < 4; r++) {
                    const float p = __expf(sf[kf][qi][r] - mnew);
                    sf[kf][qi][r] = p;
                    ls += p;
                }
            ls += __shfl_xor(ls, 16);
            ls += __shfl_xor(ls, 32);
            l_run[qi] = l_run[qi] * corr[qi] + ls;
        }
        // rescale O accumulator (corr for q_local=g*4+r lives at lane g*4+r)
#pragma unroll
        for (int mf = 0; mf < 2; mf++)
#pragma unroll
            for (int r = 0; r < 4; r++) {
                const float cf = __shfl(corr[mf], g * 4 + r);
#pragma unroll
                for (int nf = 0; nf < 4; nf++) accO[mf][nf][r] *= cf;
            }

        // write P^T -> Pt[wave] as [q][key] (bf16, swizzled), packed 2x bf16
        uint16_t* pw = &Pt[wave][0];
#pragma unroll
        for (int qi = 0; qi < 2; qi++) {
            const int q = qi * 16 + l15;
#pragma unroll
            for (int kf = 0; kf < 4; kf++) {
                const int keyb = kf * 16 + g * 4;
                const uint32_t pk0 =
                    (uint32_t)f2bf(sf[kf][qi][0]) | ((uint32_t)f2bf(sf[kf][qi][1]) << 16);
                const uint32_t pk1 =
                    (uint32_t)f2bf(sf[kf][qi][2]) | ((uint32_t)f2bf(sf[kf][qi][3]) << 16);
                const int base = q * 128 + keyb * 2;
                const int swz = (q & 7) << 4;
                *(uint32_t*)((char*)pw + (base ^ swz)) = pk0;
                *(uint32_t*)((char*)pw + ((base + 4) ^ swz)) = pk1;
            }
        }
        __syncthreads();   // Pt visible (also orders intra-wave w/r)

        // PV: O += P @ V
#pragma unroll
        for (int ks = 0; ks < 2; ks++) {
            bf16x8 pa[2];
#pragma unroll
            for (int mf = 0; mf < 2; mf++) {
                const int q = mf * 16 + l15;
                pa[mf] = *(const bf16x8*)((const char*)pw + ((q * 128 + ks * 64 + g * 16) ^
                                                             ((q & 7) << 4)));
            }
#pragma unroll
            for (int nf = 0; nf < 4; nf++) {
                const int row = nf * 16 + l15;
                bf16x8 bv = *(const bf16x8*)((const char*)Vs + row * 128 +
                                             ((ks * 64 + g * 16) ^ ((row & 7) << 4)));
#pragma unroll
                for (int mf = 0; mf < 2; mf++)
                    accO[mf][nf] = __builtin_amdgcn_mfma_f32_16x16x32_bf16(
                        pa[mf], bv, accO[mf][nf], 0, 0, 0);
            }
        }
    }

    // epilogue: normalize by l and store (bf16)
    float invl[2] = {1.f / l_run[0], 1.f / l_run[1]};
#pragma unroll
    for (int mf = 0; mf < 2; mf++)
#pragma unroll
        for (int r = 0; r < 4; r++) {
            const float iv = __shfl(invl[mf], g * 4 + r);
            const int row = b * SEQ + q0 + mf * 16 + g * 4 + r;
#pragma unroll
            for (int nf = 0; nf < 4; nf++) {
                const int col = h * HD + nf * 16 + l15;
                AO[(size_t)row * DM + col] = f2bf(accO[mf][nf][r] * iv);
            }
        }
}

// ---------------------------------------------------------------------------
extern "C" void kernel_launch(void* const* d_in, const int* in_sizes, int n_in,
                              void* d_out, int out_size, void* d_ws, size_t ws_size,
                              hipStream_t stream) {
    const float* xq = (const float*)d_in[0];
    const float* xk = (const float*)d_in[1];
    const float* xv = (const float*)d_in[2];
    const float* wq = (const float*)d_in[3];
    const float* wk = (const float*)d_in[4];
    const float* wv = (const float*)d_in[5];
    const float* wo = (const float*)d_in[6];
    float* out = (float*)d_out;
    uint16_t* ws = (uint16_t*)d_ws;

    const size_t SZ = (size_t)NB * SEQ * DM;   // 8.39M elems
    const size_t WSZ = (size_t)DM * DM;        // 1.05M elems
    uint16_t* bufA = ws;            // converted input (reused), then VT
    uint16_t* Qb = ws + SZ;
    uint16_t* Kbuf = ws + 2 * SZ;
    uint16_t* Vb = ws + 3 * SZ;     // V, then AO
    uint16_t* WqT = ws + 4 * SZ;
    uint16_t* WkT = WqT + WSZ;
    uint16_t* WvT = WkT + WSZ;
    uint16_t* WoT = WvT + WSZ;

    const dim3 tb(32, 8);
    transpose_cvt<<<dim3(32, 32, 1), tb, 0, stream>>>(wq, WqT, DM, DM);
    transpose_cvt<<<dim3(32, 32, 1), tb, 0, stream>>>(wk, WkT, DM, DM);
    transpose_cvt<<<dim3(32, 32, 1), tb, 0, stream>>>(wv, WvT, DM, DM);
    transpose_cvt<<<dim3(32, 32, 1), tb, 0, stream>>>(wo, WoT, DM, DM);

    const int cvtBlocks = (int)(SZ / (256 * 8));   // 4096
    const dim3 gg(DM / 128, NB * SEQ / 128);

    cvt_f32_bf16<<<cvtBlocks, 256, 0, stream>>>(xq, bufA);
    gemm_bf16<uint16_t><<<gg, 256, 0, stream>>>(bufA, WqT, Qb, NB * SEQ, DM, DM);

    cvt_f32_bf16<<<cvtBlocks, 256, 0, stream>>>(xk, bufA);
    gemm_bf16<uint16_t><<<gg, 256, 0, stream>>>(bufA, WkT, Kbuf, NB * SEQ, DM, DM);

    cvt_f32_bf16<<<cvtBlocks, 256, 0, stream>>>(xv, bufA);
    gemm_bf16<uint16_t><<<gg, 256, 0, stream>>>(bufA, WvT, Vb, NB * SEQ, DM, DM);

    // V^T: bufA now holds Vt[b][dglob][s]
    transpose_bf16<<<dim3(DM / 32, SEQ / 32, NB), tb, 0, stream>>>(Vb, bufA, SEQ, DM);

    // attention: reads Qb, Kbuf, bufA(VT); writes Vb (as AO)
    attn_fwd<<<dim3(SEQ / 128, NH, NB), 256, 0, stream>>>(Qb, Kbuf, bufA, Vb);

    // output projection: f32 store
    gemm_bf16<float><<<gg, 256, 0, stream>>>(Vb, WoT, out, NB * SEQ, DM, DM);
}

// Round 8
// 280.302 us; speedup vs baseline: 1.1451x; 1.1451x over previous
//
#include <hip/hip_runtime.h>
#include <stdint.h>

#define DM 1024
#define HD 64
#define NH 16
#define SEQ 2048
#define NB 4

typedef __bf16 bf16x8 __attribute__((ext_vector_type(8)));
typedef __bf16 bf16x4 __attribute__((ext_vector_type(4)));
typedef float f32x4 __attribute__((ext_vector_type(4)));

// v_exp_f32 computes 2^x natively
#define EXP2F(x) __builtin_amdgcn_exp2f(x)

__device__ __forceinline__ float bf2f(uint16_t b) {
    uint32_t u = ((uint32_t)b) << 16;
    float f;
    __builtin_memcpy(&f, &u, 4);
    return f;
}
__device__ __forceinline__ uint16_t f2bf(float f) {
    uint32_t u;
    __builtin_memcpy(&u, &f, 4);
    u += 0x7fffu + ((u >> 16) & 1u);   // RNE
    return (uint16_t)(u >> 16);
}

__device__ __forceinline__ void gll16(const void* g, void* l) {
    __builtin_amdgcn_global_load_lds(
        (const __attribute__((address_space(1))) void*)g,
        (__attribute__((address_space(3))) void*)l, 16, 0, 0);
}

// ---------------------------------------------------------------------------
// f32 -> bf16 convert, 8 elems/thread (two float4 loads, one 16B store)
// ---------------------------------------------------------------------------
__global__ __launch_bounds__(256) void cvt_f32_bf16(const float* __restrict__ in,
                                                    uint16_t* __restrict__ out) {
    const size_t i = (size_t)blockIdx.x * 256 + threadIdx.x;
    const float4* p = (const float4*)in + i * 2;
    const float4 a = p[0], b = p[1];
    uint16_t o[8] = {f2bf(a.x), f2bf(a.y), f2bf(a.z), f2bf(a.w),
                     f2bf(b.x), f2bf(b.y), f2bf(b.z), f2bf(b.w)};
    __builtin_memcpy(out + i * 8, o, 16);
}

// ---------------------------------------------------------------------------
// Weight transpose + convert: out[C][R] (bf16) = in[R][C] (f32)
// ---------------------------------------------------------------------------
__global__ void transpose_cvt(const float* __restrict__ in,
                              uint16_t* __restrict__ out, int R, int C) {
    __shared__ uint16_t t[32][33];
    const int bx = blockIdx.x * 32, by = blockIdx.y * 32;
    const int tx = threadIdx.x, ty = threadIdx.y;
#pragma unroll
    for (int i = ty; i < 32; i += 8)
        t[i][tx] = f2bf(in[(size_t)(by + i) * C + bx + tx]);
    __syncthreads();
#pragma unroll
    for (int i = ty; i < 32; i += 8)
        out[(size_t)(bx + i) * R + by + tx] = t[tx][i];
}

// ---------------------------------------------------------------------------
// bf16 transpose (for V): out[C][R] = in[R][C], batched over blockIdx.z
// ---------------------------------------------------------------------------
__global__ void transpose_bf16(const uint16_t* __restrict__ in,
                               uint16_t* __restrict__ out, int R, int C) {
    __shared__ uint16_t t[32][33];
    const int bx = blockIdx.x * 32, by = blockIdx.y * 32;
    const size_t zo = (size_t)blockIdx.z * R * C;
    in += zo; out += zo;
    const int tx = threadIdx.x, ty = threadIdx.y;
#pragma unroll
    for (int i = ty; i < 32; i += 8)
        t[i][tx] = in[(size_t)(by + i) * C + bx + tx];
    __syncthreads();
#pragma unroll
    for (int i = ty; i < 32; i += 8)
        out[(size_t)(bx + i) * R + by + tx] = t[tx][i];
}

// ---------------------------------------------------------------------------
// bf16 GEMM: C[M][N] = A[M][K] @ Bt[N][K]^T   (Bt is pre-transposed weight)
// 128x128 tile, BK=64, 256 threads (4 waves, 2x2), mfma_f32_16x16x32_bf16.
// XOR swizzle ((row&7)<<4) applied on stage-source and ds_read.
// OT = uint16_t (bf16 store) or float (f32 store, for the final GEMM).
// ---------------------------------------------------------------------------
template <typename OT>
__global__ __launch_bounds__(256) void gemm_bf16(
    const uint16_t* __restrict__ A, const uint16_t* __restrict__ Bt,
    OT* __restrict__ C, int M, int N, int K) {
    __shared__ uint16_t As[128 * 64];
    __shared__ uint16_t Bs[128 * 64];
    const int tid = threadIdx.x;
    const int wave = tid >> 6, lane = tid & 63;
    const int g = lane >> 4, l15 = lane & 15;
    const int m0 = blockIdx.y * 128, n0 = blockIdx.x * 128;
    const int wr = wave >> 1, wc = wave & 1;

    f32x4 acc[4][4];
    const f32x4 z4 = {0.f, 0.f, 0.f, 0.f};
#pragma unroll
    for (int i = 0; i < 4; i++)
#pragma unroll
        for (int j = 0; j < 4; j++) acc[i][j] = z4;

    for (int k0 = 0; k0 < K; k0 += 64) {
        __syncthreads();
#pragma unroll
        for (int i = 0; i < 4; i++) {
            const int c = wave * 4 + i;
            const int o = (c * 64 + lane) * 16;
            const int row = o >> 7, off = o & 127;
            const int soff = off ^ ((row & 7) << 4);
            gll16((const char*)A + (((size_t)(m0 + row) * K + k0) << 1) + soff,
                  (char*)As + c * 1024);
            gll16((const char*)Bt + (((size_t)(n0 + row) * K + k0) << 1) + soff,
                  (char*)Bs + c * 1024);
        }
        __syncthreads();
#pragma unroll
        for (int ks = 0; ks < 2; ks++) {
            bf16x8 a[4], b[4];
#pragma unroll
            for (int mi = 0; mi < 4; mi++) {
                const int row = wr * 64 + mi * 16 + l15;
                a[mi] = *(const bf16x8*)((const char*)As + row * 128 +
                                         ((ks * 64 + g * 16) ^ ((row & 7) << 4)));
            }
#pragma unroll
            for (int ni = 0; ni < 4; ni++) {
                const int row = wc * 64 + ni * 16 + l15;
                b[ni] = *(const bf16x8*)((const char*)Bs + row * 128 +
                                         ((ks * 64 + g * 16) ^ ((row & 7) << 4)));
            }
#pragma unroll
            for (int mi = 0; mi < 4; mi++)
#pragma unroll
                for (int ni = 0; ni < 4; ni++)
                    acc[mi][ni] = __builtin_amdgcn_mfma_f32_16x16x32_bf16(
                        a[mi], b[ni], acc[mi][ni], 0, 0, 0);
        }
    }
#pragma unroll
    for (int mi = 0; mi < 4; mi++)
#pragma unroll
        for (int ni = 0; ni < 4; ni++) {
            const int row = m0 + wr * 64 + mi * 16 + g * 4;
            const int col = n0 + wc * 64 + ni * 16 + l15;
#pragma unroll
            for (int r = 0; r < 4; r++) {
                if constexpr (sizeof(OT) == 4)
                    C[(size_t)(row + r) * N + col] = acc[mi][ni][r];
                else
                    C[(size_t)(row + r) * N + col] = f2bf(acc[mi][ni][r]);
            }
        }
}

// ---------------------------------------------------------------------------
// Flash attention fwd, v2.
//  - double-buffered K/V LDS staging: next tile's global_load_lds issued
//    BEFORE this tile's compute; ONE __syncthreads per tile (its implicit
//    vmcnt(0) drain lands after ~2k cycles of compute).
//  - swapped QK^T (S^T = mfma(K, Q^T)) -> softmax reduce = 2 shuffles.
//  - exp2-domain softmax: Q pre-scaled by 0.125*log2(e), p = exp2(s - m).
//  - defer-max (T13): skip O-rescale unless max grew by > THR (wave-voted).
//  - P -> per-wave LDS via (__bf16) casts + ds_write_b64 (memcpy both sides
//    so intra-wave W->R dependency is alias-visible; no barrier needed).
//  - setprio(1) around MFMA clusters (T5).
// Block: 256 thr = 4 waves; 32 q-rows/wave; KV tile = 64.
// ---------------------------------------------------------------------------
__global__ __launch_bounds__(256) void attn_fwd(
    const uint16_t* __restrict__ Q, const uint16_t* __restrict__ Kb,
    const uint16_t* __restrict__ Vt, uint16_t* __restrict__ AO) {
    __shared__ uint16_t Ks[2][64 * 64];    // [key][d]   swizzled
    __shared__ uint16_t Vs[2][64 * 64];    // [d][key]   swizzled
    __shared__ uint16_t Pt[4][32 * 64];    // per-wave [q][key] swizzled
    const int tid = threadIdx.x;
    const int wave = tid >> 6, lane = tid & 63;
    const int g = lane >> 4, l15 = lane & 15;
    const int qt = blockIdx.x, h = blockIdx.y, b = blockIdx.z;
    const int q0 = qt * 128 + wave * 32;   // seq-local
    const int NT = SEQ / 64;
    const float THR = 12.0f;               // log2-domain defer-max threshold

    // per-lane staging byte offsets (kt=0); lds chunk bases are wave-uniform
    size_t kglob[2], vglob[2];
    int ldsOff[2];
#pragma unroll
    for (int i = 0; i < 2; i++) {
        const int c = wave * 2 + i;
        const int o = (c * 64 + lane) * 16;
        const int row = o >> 7, off = o & 127;
        const int soff = off ^ ((row & 7) << 4);
        kglob[i] = (((size_t)(b * SEQ + row) * DM + h * HD) << 1) + soff;
        vglob[i] = (((size_t)(b * DM + h * HD + row) * SEQ) << 1) + soff;
        ldsOff[i] = c * 1024;
    }

    // Q fragments (B-operand for S^T), scaled by 0.125*log2(e)
    const float QSCALE = 0.125f * 1.44269504088896f;
    bf16x8 qf[2][2];
#pragma unroll
    for (int qi = 0; qi < 2; qi++)
#pragma unroll
        for (int ks = 0; ks < 2; ks++) {
            const uint16_t* src = Q + (size_t)(b * SEQ + q0 + qi * 16 + l15) * DM +
                                  h * HD + ks * 32 + g * 8;
            uint16_t tmp[8], ov[8];
            __builtin_memcpy(tmp, src, 16);
#pragma unroll
            for (int j = 0; j < 8; j++) ov[j] = f2bf(bf2f(tmp[j]) * QSCALE);
            __builtin_memcpy(&qf[qi][ks], ov, 16);
        }

    f32x4 accO[2][4];
    const f32x4 z4 = {0.f, 0.f, 0.f, 0.f};
#pragma unroll
    for (int i = 0; i < 2; i++)
#pragma unroll
        for (int j = 0; j < 4; j++) accO[i][j] = z4;
    float m_run[2] = {-1e30f, -1e30f};
    float l_run[2] = {0.f, 0.f};

    // prologue: stage tile 0 into buffer 0
#pragma unroll
    for (int i = 0; i < 2; i++) {
        gll16((const char*)Kb + kglob[i], (char*)Ks[0] + ldsOff[i]);
        gll16((const char*)Vt + vglob[i], (char*)Vs[0] + ldsOff[i]);
    }
    __syncthreads();

    for (int kt = 0; kt < NT; kt++) {
        const int cur = kt & 1;
        // issue next tile's staging into the other buffer (drained at the
        // barrier at the END of this iteration)
        if (kt + 1 < NT) {
            const size_t kadv = (size_t)(kt + 1) * (64 * DM * 2);
            const size_t vadv = (size_t)(kt + 1) * (64 * 2);
#pragma unroll
            for (int i = 0; i < 2; i++) {
                gll16((const char*)Kb + kglob[i] + kadv, (char*)Ks[cur ^ 1] + ldsOff[i]);
                gll16((const char*)Vt + vglob[i] + vadv, (char*)Vs[cur ^ 1] + ldsOff[i]);
            }
        }
        const uint16_t* ksrc = Ks[cur];
        const uint16_t* vsrc = Vs[cur];

        // S^T = K . Q^T : frags sf[kf][qi]; lane holds q=l15(+16qi), key=g*4+r(+16kf)
        f32x4 sf[4][2];
#pragma unroll
        for (int kf = 0; kf < 4; kf++)
#pragma unroll
            for (int qi = 0; qi < 2; qi++) sf[kf][qi] = z4;
        __builtin_amdgcn_s_setprio(1);
#pragma unroll
        for (int ks = 0; ks < 2; ks++)
#pragma unroll
            for (int kf = 0; kf < 4; kf++) {
                const int row = kf * 16 + l15;
                bf16x8 a = *(const bf16x8*)((const char*)ksrc + row * 128 +
                                            ((ks * 64 + g * 16) ^ ((row & 7) << 4)));
#pragma unroll
                for (int qi = 0; qi < 2; qi++)
                    sf[kf][qi] = __builtin_amdgcn_mfma_f32_16x16x32_bf16(
                        a, qf[qi][ks], sf[kf][qi], 0, 0, 0);
            }
        __builtin_amdgcn_s_setprio(0);

        // tile max per q-column (16 values in-lane + 2 shuffles)
        float mx[2];
#pragma unroll
        for (int qi = 0; qi < 2; qi++) {
            float m01 = fmaxf(fmaxf(sf[0][qi][0], sf[0][qi][1]),
                              fmaxf(sf[0][qi][2], sf[0][qi][3]));
            float m23 = fmaxf(fmaxf(sf[1][qi][0], sf[1][qi][1]),
                              fmaxf(sf[1][qi][2], sf[1][qi][3]));
            float m45 = fmaxf(fmaxf(sf[2][qi][0], sf[2][qi][1]),
                              fmaxf(sf[2][qi][2], sf[2][qi][3]));
            float m67 = fmaxf(fmaxf(sf[3][qi][0], sf[3][qi][1]),
                              fmaxf(sf[3][qi][2], sf[3][qi][3]));
            float m = fmaxf(fmaxf(m01, m23), fmaxf(m45, m67));
            m = fmaxf(m, __shfl_xor(m, 16));
            m = fmaxf(m, __shfl_xor(m, 32));
            mx[qi] = m;
        }

        // defer-max: rescale only when max grew past THR (wave-uniform vote)
        const int grew = (mx[0] - m_run[0] > THR) || (mx[1] - m_run[1] > THR);
        if (__any(grew)) {
            float corr[2];
#pragma unroll
            for (int qi = 0; qi < 2; qi++) {
                const float mnew = fmaxf(m_run[qi], mx[qi]);
                corr[qi] = EXP2F(m_run[qi] - mnew);
                m_run[qi] = mnew;
                l_run[qi] *= corr[qi];
            }
#pragma unroll
            for (int mf = 0; mf < 2; mf++)
#pragma unroll
                for (int r = 0; r < 4; r++) {
                    const float cf = __shfl(corr[mf], g * 4 + r);
#pragma unroll
                    for (int nf = 0; nf < 4; nf++) accO[mf][nf][r] *= cf;
                }
        }

        // p = exp2(s - m), row-sum into l_run
#pragma unroll
        for (int qi = 0; qi < 2; qi++) {
            float ls = 0.f;
#pragma unroll
            for (int kf = 0; kf < 4; kf++)
#pragma unroll
                for (int r = 0; r < 4; r++) {
                    const float p = EXP2F(sf[kf][qi][r] - m_run[qi]);
                    sf[kf][qi][r] = p;
                    ls += p;
                }
            ls += __shfl_xor(ls, 16);
            ls += __shfl_xor(ls, 32);
            l_run[qi] += ls;
        }

        // write P^T -> Pt[wave] as [q][key] bf16, swizzled; one b64 per (qi,kf)
        uint16_t* pw = &Pt[wave][0];
#pragma unroll
        for (int qi = 0; qi < 2; qi++) {
            const int q = qi * 16 + l15;
            const int swz = (q & 7) << 4;
            const int qb = q * 128;
#pragma unroll
            for (int kf = 0; kf < 4; kf++) {
                bf16x4 pv;
                pv[0] = (__bf16)sf[kf][qi][0];
                pv[1] = (__bf16)sf[kf][qi][1];
                pv[2] = (__bf16)sf[kf][qi][2];
                pv[3] = (__bf16)sf[kf][qi][3];
                const int base = qb + 32 * kf + 8 * g;
                __builtin_memcpy((char*)pw + (base ^ swz), &pv, 8);
            }
        }
        // no barrier: Pt is per-wave; memcpy accesses keep the W->R dep visible

        // PV: O += P @ V
        __builtin_amdgcn_s_setprio(1);
#pragma unroll
        for (int ks = 0; ks < 2; ks++) {
            bf16x8 pa[2];
#pragma unroll
            for (int mf = 0; mf < 2; mf++) {
                const int q = mf * 16 + l15;
                __builtin_memcpy(&pa[mf],
                                 (const char*)pw + ((q * 128 + ks * 64 + g * 16) ^
                                                    ((q & 7) << 4)),
                                 16);
            }
#pragma unroll
            for (int nf = 0; nf < 4; nf++) {
                const int row = nf * 16 + l15;
                bf16x8 bv = *(const bf16x8*)((const char*)vsrc + row * 128 +
                                             ((ks * 64 + g * 16) ^ ((row & 7) << 4)));
#pragma unroll
                for (int mf = 0; mf < 2; mf++)
                    accO[mf][nf] = __builtin_amdgcn_mfma_f32_16x16x32_bf16(
                        pa[mf], bv, accO[mf][nf], 0, 0, 0);
            }
        }
        __builtin_amdgcn_s_setprio(0);

        // single barrier per tile: implicit vmcnt(0) drains next-tile staging,
        // and releases this tile's buffers for overwrite
        __syncthreads();
    }

    // epilogue: normalize by l and store (bf16)
    float invl[2] = {1.f / l_run[0], 1.f / l_run[1]};
#pragma unroll
    for (int mf = 0; mf < 2; mf++)
#pragma unroll
        for (int r = 0; r < 4; r++) {
            const float iv = __shfl(invl[mf], g * 4 + r);
            const int row = b * SEQ + q0 + mf * 16 + g * 4 + r;
#pragma unroll
            for (int nf = 0; nf < 4; nf++) {
                const int col = h * HD + nf * 16 + l15;
                AO[(size_t)row * DM + col] = f2bf(accO[mf][nf][r] * iv);
            }
        }
}

// ---------------------------------------------------------------------------
extern "C" void kernel_launch(void* const* d_in, const int* in_sizes, int n_in,
                              void* d_out, int out_size, void* d_ws, size_t ws_size,
                              hipStream_t stream) {
    const float* xq = (const float*)d_in[0];
    const float* xk = (const float*)d_in[1];
    const float* xv = (const float*)d_in[2];
    const float* wq = (const float*)d_in[3];
    const float* wk = (const float*)d_in[4];
    const float* wv = (const float*)d_in[5];
    const float* wo = (const float*)d_in[6];
    float* out = (float*)d_out;
    uint16_t* ws = (uint16_t*)d_ws;

    const size_t SZ = (size_t)NB * SEQ * DM;   // 8.39M elems
    const size_t WSZ = (size_t)DM * DM;        // 1.05M elems
    uint16_t* bufA = ws;            // converted input (reused), then VT
    uint16_t* Qb = ws + SZ;
    uint16_t* Kbuf = ws + 2 * SZ;
    uint16_t* Vb = ws + 3 * SZ;     // V, then AO
    uint16_t* WqT = ws + 4 * SZ;
    uint16_t* WkT = WqT + WSZ;
    uint16_t* WvT = WkT + WSZ;
    uint16_t* WoT = WvT + WSZ;

    const dim3 tb(32, 8);
    transpose_cvt<<<dim3(32, 32, 1), tb, 0, stream>>>(wq, WqT, DM, DM);
    transpose_cvt<<<dim3(32, 32, 1), tb, 0, stream>>>(wk, WkT, DM, DM);
    transpose_cvt<<<dim3(32, 32, 1), tb, 0, stream>>>(wv, WvT, DM, DM);
    transpose_cvt<<<dim3(32, 32, 1), tb, 0, stream>>>(wo, WoT, DM, DM);

    const int cvtBlocks = (int)(SZ / (256 * 8));   // 4096
    const dim3 gg(DM / 128, NB * SEQ / 128);

    cvt_f32_bf16<<<cvtBlocks, 256, 0, stream>>>(xq, bufA);
    gemm_bf16<uint16_t><<<gg, 256, 0, stream>>>(bufA, WqT, Qb, NB * SEQ, DM, DM);

    cvt_f32_bf16<<<cvtBlocks, 256, 0, stream>>>(xk, bufA);
    gemm_bf16<uint16_t><<<gg, 256, 0, stream>>>(bufA, WkT, Kbuf, NB * SEQ, DM, DM);

    cvt_f32_bf16<<<cvtBlocks, 256, 0, stream>>>(xv, bufA);
    gemm_bf16<uint16_t><<<gg, 256, 0, stream>>>(bufA, WvT, Vb, NB * SEQ, DM, DM);

    // V^T: bufA now holds Vt[b][dglob][s]
    transpose_bf16<<<dim3(DM / 32, SEQ / 32, NB), tb, 0, stream>>>(Vb, bufA, SEQ, DM);

    // attention: reads Qb, Kbuf, bufA(VT); writes Vb (as AO)
    attn_fwd<<<dim3(SEQ / 128, NH, NB), 256, 0, stream>>>(Qb, Kbuf, bufA, Vb);

    // output projection: f32 store
    gemm_bf16<float><<<gg, 256, 0, stream>>>(Vb, WoT, out, NB * SEQ, DM, DM);
}

// Round 9
// 272.964 us; speedup vs baseline: 1.1759x; 1.0269x over previous
//
#include <hip/hip_runtime.h>
#include <stdint.h>

#define DM 1024
#define HD 64
#define NH 16
#define SEQ 2048
#define NB 4

typedef __bf16 bf16x8 __attribute__((ext_vector_type(8)));
typedef __bf16 bf16x4 __attribute__((ext_vector_type(4)));
typedef float f32x4 __attribute__((ext_vector_type(4)));

// v_exp_f32 computes 2^x natively
#define EXP2F(x) __builtin_amdgcn_exp2f(x)

__device__ __forceinline__ float bf2f(uint16_t b) {
    uint32_t u = ((uint32_t)b) << 16;
    float f;
    __builtin_memcpy(&f, &u, 4);
    return f;
}
__device__ __forceinline__ uint16_t f2bf(float f) {
    uint32_t u;
    __builtin_memcpy(&u, &f, 4);
    u += 0x7fffu + ((u >> 16) & 1u);   // RNE
    return (uint16_t)(u >> 16);
}

__device__ __forceinline__ void gll16(const void* g, void* l) {
    __builtin_amdgcn_global_load_lds(
        (const __attribute__((address_space(1))) void*)g,
        (__attribute__((address_space(3))) void*)l, 16, 0, 0);
}

// ---------------------------------------------------------------------------
// f32 -> bf16 convert, 8 elems/thread (two float4 loads, one 16B store)
// ---------------------------------------------------------------------------
__global__ __launch_bounds__(256) void cvt_f32_bf16(const float* __restrict__ in,
                                                    uint16_t* __restrict__ out) {
    const size_t i = (size_t)blockIdx.x * 256 + threadIdx.x;
    const float4* p = (const float4*)in + i * 2;
    const float4 a = p[0], b = p[1];
    uint16_t o[8] = {f2bf(a.x), f2bf(a.y), f2bf(a.z), f2bf(a.w),
                     f2bf(b.x), f2bf(b.y), f2bf(b.z), f2bf(b.w)};
    __builtin_memcpy(out + i * 8, o, 16);
}

// ---------------------------------------------------------------------------
// Weight transpose + convert: out[C][R] (bf16) = in[R][C] (f32)
// ---------------------------------------------------------------------------
__global__ void transpose_cvt(const float* __restrict__ in,
                              uint16_t* __restrict__ out, int R, int C) {
    __shared__ uint16_t t[32][33];
    const int bx = blockIdx.x * 32, by = blockIdx.y * 32;
    const int tx = threadIdx.x, ty = threadIdx.y;
#pragma unroll
    for (int i = ty; i < 32; i += 8)
        t[i][tx] = f2bf(in[(size_t)(by + i) * C + bx + tx]);
    __syncthreads();
#pragma unroll
    for (int i = ty; i < 32; i += 8)
        out[(size_t)(bx + i) * R + by + tx] = t[tx][i];
}

// ---------------------------------------------------------------------------
// bf16 transpose (for V): out[C][R] = in[R][C], batched over blockIdx.z
// ---------------------------------------------------------------------------
__global__ void transpose_bf16(const uint16_t* __restrict__ in,
                               uint16_t* __restrict__ out, int R, int C) {
    __shared__ uint16_t t[32][33];
    const int bx = blockIdx.x * 32, by = blockIdx.y * 32;
    const size_t zo = (size_t)blockIdx.z * R * C;
    in += zo; out += zo;
    const int tx = threadIdx.x, ty = threadIdx.y;
#pragma unroll
    for (int i = ty; i < 32; i += 8)
        t[i][tx] = in[(size_t)(by + i) * C + bx + tx];
    __syncthreads();
#pragma unroll
    for (int i = ty; i < 32; i += 8)
        out[(size_t)(bx + i) * R + by + tx] = t[tx][i];
}

// ---------------------------------------------------------------------------
// bf16 GEMM: C[M][N] = A[M][K] @ Bt[N][K]^T   (Bt is pre-transposed weight)
// 128x128 tile, BK=64, 256 threads (4 waves, 2x2), mfma_f32_16x16x32_bf16.
// XOR swizzle ((row&7)<<4) applied on stage-source and ds_read.
// OT = uint16_t (bf16 store) or float (f32 store, for the final GEMM).
// ---------------------------------------------------------------------------
template <typename OT>
__global__ __launch_bounds__(256) void gemm_bf16(
    const uint16_t* __restrict__ A, const uint16_t* __restrict__ Bt,
    OT* __restrict__ C, int M, int N, int K) {
    __shared__ uint16_t As[128 * 64];
    __shared__ uint16_t Bs[128 * 64];
    const int tid = threadIdx.x;
    const int wave = tid >> 6, lane = tid & 63;
    const int g = lane >> 4, l15 = lane & 15;
    const int m0 = blockIdx.y * 128, n0 = blockIdx.x * 128;
    const int wr = wave >> 1, wc = wave & 1;

    f32x4 acc[4][4];
    const f32x4 z4 = {0.f, 0.f, 0.f, 0.f};
#pragma unroll
    for (int i = 0; i < 4; i++)
#pragma unroll
        for (int j = 0; j < 4; j++) acc[i][j] = z4;

    for (int k0 = 0; k0 < K; k0 += 64) {
        __syncthreads();
#pragma unroll
        for (int i = 0; i < 4; i++) {
            const int c = wave * 4 + i;
            const int o = (c * 64 + lane) * 16;
            const int row = o >> 7, off = o & 127;
            const int soff = off ^ ((row & 7) << 4);
            gll16((const char*)A + (((size_t)(m0 + row) * K + k0) << 1) + soff,
                  (char*)As + c * 1024);
            gll16((const char*)Bt + (((size_t)(n0 + row) * K + k0) << 1) + soff,
                  (char*)Bs + c * 1024);
        }
        __syncthreads();
#pragma unroll
        for (int ks = 0; ks < 2; ks++) {
            bf16x8 a[4], b[4];
#pragma unroll
            for (int mi = 0; mi < 4; mi++) {
                const int row = wr * 64 + mi * 16 + l15;
                a[mi] = *(const bf16x8*)((const char*)As + row * 128 +
                                         ((ks * 64 + g * 16) ^ ((row & 7) << 4)));
            }
#pragma unroll
            for (int ni = 0; ni < 4; ni++) {
                const int row = wc * 64 + ni * 16 + l15;
                b[ni] = *(const bf16x8*)((const char*)Bs + row * 128 +
                                         ((ks * 64 + g * 16) ^ ((row & 7) << 4)));
            }
#pragma unroll
            for (int mi = 0; mi < 4; mi++)
#pragma unroll
                for (int ni = 0; ni < 4; ni++)
                    acc[mi][ni] = __builtin_amdgcn_mfma_f32_16x16x32_bf16(
                        a[mi], b[ni], acc[mi][ni], 0, 0, 0);
        }
    }
#pragma unroll
    for (int mi = 0; mi < 4; mi++)
#pragma unroll
        for (int ni = 0; ni < 4; ni++) {
            const int row = m0 + wr * 64 + mi * 16 + g * 4;
            const int col = n0 + wc * 64 + ni * 16 + l15;
#pragma unroll
            for (int r = 0; r < 4; r++) {
                if constexpr (sizeof(OT) == 4)
                    C[(size_t)(row + r) * N + col] = acc[mi][ni][r];
                else
                    C[(size_t)(row + r) * N + col] = f2bf(acc[mi][ni][r]);
            }
        }
}

// ---------------------------------------------------------------------------
// Flash attention fwd, v3.
//  - 512 threads = 8 waves, 256 q-rows/block -> grid 512 blocks = exactly
//    2 blocks/CU (LDS 64 KiB and VGPR both allow 2) -> ALL blocks
//    co-resident, no straggler tail, 16 waves/CU.
//  - 8 waves share each K/V tile staging (1 K-chunk + 1 V-chunk per wave).
//  - double-buffered K/V; next tile's global_load_lds issued BEFORE compute;
//    ONE __syncthreads per tile.
//  - swapped QK^T (S^T = mfma(K, Q^T)); exp2-domain softmax; defer-max;
//    per-lane partial row-sums (cross-lane l reduce deferred to epilogue).
//  - P -> per-wave LDS (no barrier); setprio around MFMA clusters.
// ---------------------------------------------------------------------------
__global__ __launch_bounds__(512) void attn_fwd(
    const uint16_t* __restrict__ Q, const uint16_t* __restrict__ Kb,
    const uint16_t* __restrict__ Vt, uint16_t* __restrict__ AO) {
    __shared__ uint16_t Ks[2][64 * 64];    // [key][d]   swizzled
    __shared__ uint16_t Vs[2][64 * 64];    // [d][key]   swizzled
    __shared__ uint16_t Pt[8][32 * 64];    // per-wave [q][key] swizzled
    const int tid = threadIdx.x;
    const int wave = tid >> 6, lane = tid & 63;
    const int g = lane >> 4, l15 = lane & 15;
    const int qt = blockIdx.x, h = blockIdx.y, b = blockIdx.z;
    const int q0 = qt * 256 + wave * 32;   // seq-local
    const int NT = SEQ / 64;
    const float THR = 12.0f;               // log2-domain defer-max threshold

    // per-lane staging byte offsets (kt=0); one 1KiB chunk per wave for each
    // of K and V (8 waves cover the 8 KiB tile)
    size_t kglob, vglob;
    int ldsOff;
    {
        const int c = wave;
        const int o = (c * 64 + lane) * 16;
        const int row = o >> 7, off = o & 127;
        const int soff = off ^ ((row & 7) << 4);
        kglob = (((size_t)(b * SEQ + row) * DM + h * HD) << 1) + soff;
        vglob = (((size_t)(b * DM + h * HD + row) * SEQ) << 1) + soff;
        ldsOff = c * 1024;
    }

    // Q fragments (B-operand for S^T), scaled by 0.125*log2(e)
    const float QSCALE = 0.125f * 1.44269504088896f;
    bf16x8 qf[2][2];
#pragma unroll
    for (int qi = 0; qi < 2; qi++)
#pragma unroll
        for (int ks = 0; ks < 2; ks++) {
            const uint16_t* src = Q + (size_t)(b * SEQ + q0 + qi * 16 + l15) * DM +
                                  h * HD + ks * 32 + g * 8;
            uint16_t tmp[8], ov[8];
            __builtin_memcpy(tmp, src, 16);
#pragma unroll
            for (int j = 0; j < 8; j++) ov[j] = f2bf(bf2f(tmp[j]) * QSCALE);
            __builtin_memcpy(&qf[qi][ks], ov, 16);
        }

    f32x4 accO[2][4];
    const f32x4 z4 = {0.f, 0.f, 0.f, 0.f};
#pragma unroll
    for (int i = 0; i < 2; i++)
#pragma unroll
        for (int j = 0; j < 4; j++) accO[i][j] = z4;
    float m_run[2] = {-1e30f, -1e30f};
    float l_run[2] = {0.f, 0.f};   // per-lane partial (reduced in epilogue)

    // prologue: stage tile 0 into buffer 0
    gll16((const char*)Kb + kglob, (char*)Ks[0] + ldsOff);
    gll16((const char*)Vt + vglob, (char*)Vs[0] + ldsOff);
    __syncthreads();

    for (int kt = 0; kt < NT; kt++) {
        const int cur = kt & 1;
        // issue next tile's staging into the other buffer (drained at the
        // barrier at the END of this iteration)
        if (kt + 1 < NT) {
            const size_t kadv = (size_t)(kt + 1) * (64 * DM * 2);
            const size_t vadv = (size_t)(kt + 1) * (64 * 2);
            gll16((const char*)Kb + kglob + kadv, (char*)Ks[cur ^ 1] + ldsOff);
            gll16((const char*)Vt + vglob + vadv, (char*)Vs[cur ^ 1] + ldsOff);
        }
        const uint16_t* ksrc = Ks[cur];
        const uint16_t* vsrc = Vs[cur];

        // S^T = K . Q^T : frags sf[kf][qi]; lane holds q=l15(+16qi), key=g*4+r(+16kf)
        f32x4 sf[4][2];
#pragma unroll
        for (int kf = 0; kf < 4; kf++)
#pragma unroll
            for (int qi = 0; qi < 2; qi++) sf[kf][qi] = z4;
        __builtin_amdgcn_s_setprio(1);
#pragma unroll
        for (int ks = 0; ks < 2; ks++)
#pragma unroll
            for (int kf = 0; kf < 4; kf++) {
                const int row = kf * 16 + l15;
                bf16x8 a = *(const bf16x8*)((const char*)ksrc + row * 128 +
                                            ((ks * 64 + g * 16) ^ ((row & 7) << 4)));
#pragma unroll
                for (int qi = 0; qi < 2; qi++)
                    sf[kf][qi] = __builtin_amdgcn_mfma_f32_16x16x32_bf16(
                        a, qf[qi][ks], sf[kf][qi], 0, 0, 0);
            }
        __builtin_amdgcn_s_setprio(0);

        // tile max per q-column (16 values in-lane + 2 shuffles)
        float mx[2];
#pragma unroll
        for (int qi = 0; qi < 2; qi++) {
            float m01 = fmaxf(fmaxf(sf[0][qi][0], sf[0][qi][1]),
                              fmaxf(sf[0][qi][2], sf[0][qi][3]));
            float m23 = fmaxf(fmaxf(sf[1][qi][0], sf[1][qi][1]),
                              fmaxf(sf[1][qi][2], sf[1][qi][3]));
            float m45 = fmaxf(fmaxf(sf[2][qi][0], sf[2][qi][1]),
                              fmaxf(sf[2][qi][2], sf[2][qi][3]));
            float m67 = fmaxf(fmaxf(sf[3][qi][0], sf[3][qi][1]),
                              fmaxf(sf[3][qi][2], sf[3][qi][3]));
            float m = fmaxf(fmaxf(m01, m23), fmaxf(m45, m67));
            m = fmaxf(m, __shfl_xor(m, 16));
            m = fmaxf(m, __shfl_xor(m, 32));
            mx[qi] = m;
        }

        // defer-max: rescale only when max grew past THR (wave-uniform vote)
        const int grew = (mx[0] - m_run[0] > THR) || (mx[1] - m_run[1] > THR);
        if (__any(grew)) {
            float corr[2];
#pragma unroll
            for (int qi = 0; qi < 2; qi++) {
                const float mnew = fmaxf(m_run[qi], mx[qi]);
                corr[qi] = EXP2F(m_run[qi] - mnew);
                m_run[qi] = mnew;
                l_run[qi] *= corr[qi];
            }
#pragma unroll
            for (int mf = 0; mf < 2; mf++)
#pragma unroll
                for (int r = 0; r < 4; r++) {
                    const float cf = __shfl(corr[mf], g * 4 + r);
#pragma unroll
                    for (int nf = 0; nf < 4; nf++) accO[mf][nf][r] *= cf;
                }
        }

        // p = exp2(s - m), per-lane partial row-sum into l_run
#pragma unroll
        for (int qi = 0; qi < 2; qi++) {
            float ls = 0.f;
#pragma unroll
            for (int kf = 0; kf < 4; kf++)
#pragma unroll
                for (int r = 0; r < 4; r++) {
                    const float p = EXP2F(sf[kf][qi][r] - m_run[qi]);
                    sf[kf][qi][r] = p;
                    ls += p;
                }
            l_run[qi] += ls;
        }

        // write P^T -> Pt[wave] as [q][key] bf16, swizzled; one b64 per (qi,kf)
        uint16_t* pw = &Pt[wave][0];
#pragma unroll
        for (int qi = 0; qi < 2; qi++) {
            const int q = qi * 16 + l15;
            const int swz = (q & 7) << 4;
            const int qb = q * 128;
#pragma unroll
            for (int kf = 0; kf < 4; kf++) {
                bf16x4 pv;
                pv[0] = (__bf16)sf[kf][qi][0];
                pv[1] = (__bf16)sf[kf][qi][1];
                pv[2] = (__bf16)sf[kf][qi][2];
                pv[3] = (__bf16)sf[kf][qi][3];
                const int base = qb + 32 * kf + 8 * g;
                __builtin_memcpy((char*)pw + (base ^ swz), &pv, 8);
            }
        }
        // no barrier: Pt is per-wave; memcpy accesses keep the W->R dep visible

        // PV: O += P @ V
        __builtin_amdgcn_s_setprio(1);
#pragma unroll
        for (int ks = 0; ks < 2; ks++) {
            bf16x8 pa[2];
#pragma unroll
            for (int mf = 0; mf < 2; mf++) {
                const int q = mf * 16 + l15;
                __builtin_memcpy(&pa[mf],
                                 (const char*)pw + ((q * 128 + ks * 64 + g * 16) ^
                                                    ((q & 7) << 4)),
                                 16);
            }
#pragma unroll
            for (int nf = 0; nf < 4; nf++) {
                const int row = nf * 16 + l15;
                bf16x8 bv = *(const bf16x8*)((const char*)vsrc + row * 128 +
                                             ((ks * 64 + g * 16) ^ ((row & 7) << 4)));
#pragma unroll
                for (int mf = 0; mf < 2; mf++)
                    accO[mf][nf] = __builtin_amdgcn_mfma_f32_16x16x32_bf16(
                        pa[mf], bv, accO[mf][nf], 0, 0, 0);
            }
        }
        __builtin_amdgcn_s_setprio(0);

        // single barrier per tile: implicit vmcnt(0) drains next-tile staging,
        // and releases this tile's buffers for overwrite
        __syncthreads();
    }

    // epilogue: finish l reduction across the 4 key-group lanes, normalize
#pragma unroll
    for (int qi = 0; qi < 2; qi++) {
        l_run[qi] += __shfl_xor(l_run[qi], 16);
        l_run[qi] += __shfl_xor(l_run[qi], 32);
    }
    float invl[2] = {1.f / l_run[0], 1.f / l_run[1]};
#pragma unroll
    for (int mf = 0; mf < 2; mf++)
#pragma unroll
        for (int r = 0; r < 4; r++) {
            const float iv = __shfl(invl[mf], g * 4 + r);
            const int row = b * SEQ + q0 + mf * 16 + g * 4 + r;
#pragma unroll
            for (int nf = 0; nf < 4; nf++) {
                const int col = h * HD + nf * 16 + l15;
                AO[(size_t)row * DM + col] = f2bf(accO[mf][nf][r] * iv);
            }
        }
}

// ---------------------------------------------------------------------------
extern "C" void kernel_launch(void* const* d_in, const int* in_sizes, int n_in,
                              void* d_out, int out_size, void* d_ws, size_t ws_size,
                              hipStream_t stream) {
    const float* xq = (const float*)d_in[0];
    const float* xk = (const float*)d_in[1];
    const float* xv = (const float*)d_in[2];
    const float* wq = (const float*)d_in[3];
    const float* wk = (const float*)d_in[4];
    const float* wv = (const float*)d_in[5];
    const float* wo = (const float*)d_in[6];
    float* out = (float*)d_out;
    uint16_t* ws = (uint16_t*)d_ws;

    const size_t SZ = (size_t)NB * SEQ * DM;   // 8.39M elems
    const size_t WSZ = (size_t)DM * DM;        // 1.05M elems
    uint16_t* bufA = ws;            // converted input (reused), then VT
    uint16_t* Qb = ws + SZ;
    uint16_t* Kbuf = ws + 2 * SZ;
    uint16_t* Vb = ws + 3 * SZ;     // V, then AO
    uint16_t* WqT = ws + 4 * SZ;
    uint16_t* WkT = WqT + WSZ;
    uint16_t* WvT = WkT + WSZ;
    uint16_t* WoT = WvT + WSZ;

    const dim3 tb(32, 8);
    transpose_cvt<<<dim3(32, 32, 1), tb, 0, stream>>>(wq, WqT, DM, DM);
    transpose_cvt<<<dim3(32, 32, 1), tb, 0, stream>>>(wk, WkT, DM, DM);
    transpose_cvt<<<dim3(32, 32, 1), tb, 0, stream>>>(wv, WvT, DM, DM);
    transpose_cvt<<<dim3(32, 32, 1), tb, 0, stream>>>(wo, WoT, DM, DM);

    const int cvtBlocks = (int)(SZ / (256 * 8));   // 4096
    const dim3 gg(DM / 128, NB * SEQ / 128);

    cvt_f32_bf16<<<cvtBlocks, 256, 0, stream>>>(xq, bufA);
    gemm_bf16<uint16_t><<<gg, 256, 0, stream>>>(bufA, WqT, Qb, NB * SEQ, DM, DM);

    cvt_f32_bf16<<<cvtBlocks, 256, 0, stream>>>(xk, bufA);
    gemm_bf16<uint16_t><<<gg, 256, 0, stream>>>(bufA, WkT, Kbuf, NB * SEQ, DM, DM);

    cvt_f32_bf16<<<cvtBlocks, 256, 0, stream>>>(xv, bufA);
    gemm_bf16<uint16_t><<<gg, 256, 0, stream>>>(bufA, WvT, Vb, NB * SEQ, DM, DM);

    // V^T: bufA now holds Vt[b][dglob][s]
    transpose_bf16<<<dim3(DM / 32, SEQ / 32, NB), tb, 0, stream>>>(Vb, bufA, SEQ, DM);

    // attention: reads Qb, Kbuf, bufA(VT); writes Vb (as AO)
    attn_fwd<<<dim3(SEQ / 256, NH, NB), 512, 0, stream>>>(Qb, Kbuf, bufA, Vb);

    // output projection: f32 store
    gemm_bf16<float><<<gg, 256, 0, stream>>>(Vb, WoT, out, NB * SEQ, DM, DM);
}

// Round 10
// 264.019 us; speedup vs baseline: 1.2157x; 1.0339x over previous
//
#include <hip/hip_runtime.h>
#include <stdint.h>

#define DM 1024
#define HD 64
#define NH 16
#define SEQ 2048
#define NB 4

typedef __bf16 bf16x8 __attribute__((ext_vector_type(8)));
typedef __bf16 bf16x4 __attribute__((ext_vector_type(4)));
typedef float f32x4 __attribute__((ext_vector_type(4)));

// v_exp_f32 computes 2^x natively
#define EXP2F(x) __builtin_amdgcn_exp2f(x)

__device__ __forceinline__ float bf2f(uint16_t b) {
    uint32_t u = ((uint32_t)b) << 16;
    float f;
    __builtin_memcpy(&f, &u, 4);
    return f;
}
__device__ __forceinline__ uint16_t f2bf(float f) {
    uint32_t u;
    __builtin_memcpy(&u, &f, 4);
    u += 0x7fffu + ((u >> 16) & 1u);   // RNE
    return (uint16_t)(u >> 16);
}

__device__ __forceinline__ void gll16(const void* g, void* l) {
    __builtin_amdgcn_global_load_lds(
        (const __attribute__((address_space(1))) void*)g,
        (__attribute__((address_space(3))) void*)l, 16, 0, 0);
}

// ---------------------------------------------------------------------------
// f32 -> bf16 convert, 8 elems/thread (two float4 loads, one 16B store)
// ---------------------------------------------------------------------------
__global__ __launch_bounds__(256) void cvt_f32_bf16(const float* __restrict__ in,
                                                    uint16_t* __restrict__ out) {
    const size_t i = (size_t)blockIdx.x * 256 + threadIdx.x;
    const float4* p = (const float4*)in + i * 2;
    const float4 a = p[0], b = p[1];
    uint16_t o[8] = {f2bf(a.x), f2bf(a.y), f2bf(a.z), f2bf(a.w),
                     f2bf(b.x), f2bf(b.y), f2bf(b.z), f2bf(b.w)};
    __builtin_memcpy(out + i * 8, o, 16);
}

// ---------------------------------------------------------------------------
// Weight transpose + convert: out[C][R] (bf16) = in[R][C] (f32)
// ---------------------------------------------------------------------------
__global__ void transpose_cvt(const float* __restrict__ in,
                              uint16_t* __restrict__ out, int R, int C) {
    __shared__ uint16_t t[32][33];
    const int bx = blockIdx.x * 32, by = blockIdx.y * 32;
    const int tx = threadIdx.x, ty = threadIdx.y;
#pragma unroll
    for (int i = ty; i < 32; i += 8)
        t[i][tx] = f2bf(in[(size_t)(by + i) * C + bx + tx]);
    __syncthreads();
#pragma unroll
    for (int i = ty; i < 32; i += 8)
        out[(size_t)(bx + i) * R + by + tx] = t[tx][i];
}

// ---------------------------------------------------------------------------
// bf16 transpose (for V): out[C][R] = in[R][C], batched over blockIdx.z
// ---------------------------------------------------------------------------
__global__ void transpose_bf16(const uint16_t* __restrict__ in,
                               uint16_t* __restrict__ out, int R, int C) {
    __shared__ uint16_t t[32][33];
    const int bx = blockIdx.x * 32, by = blockIdx.y * 32;
    const size_t zo = (size_t)blockIdx.z * R * C;
    in += zo; out += zo;
    const int tx = threadIdx.x, ty = threadIdx.y;
#pragma unroll
    for (int i = ty; i < 32; i += 8)
        t[i][tx] = in[(size_t)(by + i) * C + bx + tx];
    __syncthreads();
#pragma unroll
    for (int i = ty; i < 32; i += 8)
        out[(size_t)(bx + i) * R + by + tx] = t[tx][i];
}

// ---------------------------------------------------------------------------
// bf16 GEMM v2: 2-phase double-buffered staging. C = A[M][K] @ Bt[N][K]^T.
// 128x128 tile, BK=64, 256 threads (4 waves, 2x2). One barrier per K-step:
// next K-step's global_load_lds issued BEFORE this step's compute.
// ---------------------------------------------------------------------------
template <typename OT>
__global__ __launch_bounds__(256) void gemm_bf16(
    const uint16_t* __restrict__ A, const uint16_t* __restrict__ Bt,
    OT* __restrict__ C, int M, int N, int K) {
    __shared__ uint16_t As[2][128 * 64];
    __shared__ uint16_t Bs[2][128 * 64];
    const int tid = threadIdx.x;
    const int wave = tid >> 6, lane = tid & 63;
    const int g = lane >> 4, l15 = lane & 15;
    const int m0 = blockIdx.y * 128, n0 = blockIdx.x * 128;
    const int wr = wave >> 1, wc = wave & 1;

    // per-lane staging addresses (k0 = 0)
    size_t aglob[4], bglob[4];
    int ldsOff[4];
#pragma unroll
    for (int i = 0; i < 4; i++) {
        const int c = wave * 4 + i;
        const int o = (c * 64 + lane) * 16;
        const int row = o >> 7, off = o & 127;
        const int soff = off ^ ((row & 7) << 4);
        aglob[i] = ((size_t)(m0 + row) * K << 1) + soff;
        bglob[i] = ((size_t)(n0 + row) * K << 1) + soff;
        ldsOff[i] = c * 1024;
    }

    f32x4 acc[4][4];
    const f32x4 z4 = {0.f, 0.f, 0.f, 0.f};
#pragma unroll
    for (int i = 0; i < 4; i++)
#pragma unroll
        for (int j = 0; j < 4; j++) acc[i][j] = z4;

    // prologue: stage k0=0 into buffer 0
#pragma unroll
    for (int i = 0; i < 4; i++) {
        gll16((const char*)A + aglob[i], (char*)As[0] + ldsOff[i]);
        gll16((const char*)Bt + bglob[i], (char*)Bs[0] + ldsOff[i]);
    }
    __syncthreads();

    for (int k0 = 0; k0 < K; k0 += 64) {
        const int cur = (k0 >> 6) & 1;
        if (k0 + 64 < K) {
            const size_t kb = (size_t)(k0 + 64) << 1;
#pragma unroll
            for (int i = 0; i < 4; i++) {
                gll16((const char*)A + aglob[i] + kb, (char*)As[cur ^ 1] + ldsOff[i]);
                gll16((const char*)Bt + bglob[i] + kb, (char*)Bs[cur ^ 1] + ldsOff[i]);
            }
        }
        const uint16_t* as = As[cur];
        const uint16_t* bs = Bs[cur];
#pragma unroll
        for (int ks = 0; ks < 2; ks++) {
            bf16x8 a[4], b[4];
#pragma unroll
            for (int mi = 0; mi < 4; mi++) {
                const int row = wr * 64 + mi * 16 + l15;
                a[mi] = *(const bf16x8*)((const char*)as + row * 128 +
                                         ((ks * 64 + g * 16) ^ ((row & 7) << 4)));
            }
#pragma unroll
            for (int ni = 0; ni < 4; ni++) {
                const int row = wc * 64 + ni * 16 + l15;
                b[ni] = *(const bf16x8*)((const char*)bs + row * 128 +
                                         ((ks * 64 + g * 16) ^ ((row & 7) << 4)));
            }
#pragma unroll
            for (int mi = 0; mi < 4; mi++)
#pragma unroll
                for (int ni = 0; ni < 4; ni++)
                    acc[mi][ni] = __builtin_amdgcn_mfma_f32_16x16x32_bf16(
                        a[mi], b[ni], acc[mi][ni], 0, 0, 0);
        }
        __syncthreads();   // drains next-step staging; releases cur buffer
    }
#pragma unroll
    for (int mi = 0; mi < 4; mi++)
#pragma unroll
        for (int ni = 0; ni < 4; ni++) {
            const int row = m0 + wr * 64 + mi * 16 + g * 4;
            const int col = n0 + wc * 64 + ni * 16 + l15;
#pragma unroll
            for (int r = 0; r < 4; r++) {
                if constexpr (sizeof(OT) == 4)
                    C[(size_t)(row + r) * N + col] = acc[mi][ni][r];
                else
                    C[(size_t)(row + r) * N + col] = f2bf(acc[mi][ni][r]);
            }
        }
}

// ---------------------------------------------------------------------------
// Flash attention fwd, v4: P stays entirely in registers.
//  - S^T = mfma(K, Q^T) with K staged in PERMUTED key order kappa(.) so each
//    lane's softmax outputs are exactly its PV B-fragment (in-lane pass-
//    through: pa[qi][ks] = {sf[ks][qi], sf[ks+2][qi]} cast to bf16).
//    kappa(rho): key[5]=rho[4], key[4:3]=rho[3:2], key[2]=rho[5],
//    key[1:0]=rho[1:0]  (softmax is key-permutation invariant).
//  - PV computed as O^T = mfma(A=V^T, B=P^T); V stays natural order.
//  - O-rescale and 1/l are per-lane scalar muls (q = lane&15) - no shfl.
//  - double-buffered K/V staging, one barrier per tile; setprio on MFMA.
//  - 4 waves (256 thr), 128 q-rows/block; grid 1024 = 4 blocks/CU (32 KiB).
//  - epilogue: O^T -> per-wave LDS bounce (reusing Ks) -> coalesced stores.
// ---------------------------------------------------------------------------
__global__ __launch_bounds__(256) void attn_fwd(
    const uint16_t* __restrict__ Q, const uint16_t* __restrict__ Kb,
    const uint16_t* __restrict__ Vt, uint16_t* __restrict__ AO) {
    __shared__ uint16_t Ks[2][64 * 64];    // [key(permuted)][d] swizzled
    __shared__ uint16_t Vs[2][64 * 64];    // [d][key(natural)] swizzled
    const int tid = threadIdx.x;
    const int wave = tid >> 6, lane = tid & 63;
    const int g = lane >> 4, l15 = lane & 15;
    const int qt = blockIdx.x, h = blockIdx.y, b = blockIdx.z;
    const int q0 = qt * 128 + wave * 32;   // seq-local
    const int NT = SEQ / 64;
    const float THR = 12.0f;               // log2-domain defer-max threshold

    // per-lane staging addresses (kt=0); chunks c = wave*2+i cover the tile
    size_t kglob[2], vglob[2];
    int ldsOff[2];
#pragma unroll
    for (int i = 0; i < 2; i++) {
        const int c = wave * 2 + i;
        const int r3 = (lane >> 3) & 7;               // rho[2:0]
        const int soff = ((lane & 7) << 4) ^ (r3 << 4);
        // K: permuted key for LDS row rho = c*8 + r3
        const int kappa = (((c >> 1) & 1) << 5) | ((c & 1) << 4) |
                          (((lane >> 5) & 1) << 3) | (((c >> 2) & 1) << 2) |
                          (r3 & 3);
        kglob[i] = (((size_t)(b * SEQ + kappa) * DM + h * HD) << 1) + soff;
        // V: natural order, row rho = d-index
        vglob[i] = (((size_t)(b * DM + h * HD + c * 8 + r3) * SEQ) << 1) + soff;
        ldsOff[i] = c * 1024;
    }

    // Q fragments (B-operand for S^T), scaled by 0.125*log2(e)
    const float QSCALE = 0.125f * 1.44269504088896f;
    bf16x8 qf[2][2];
#pragma unroll
    for (int qi = 0; qi < 2; qi++)
#pragma unroll
        for (int ks = 0; ks < 2; ks++) {
            const uint16_t* src = Q + (size_t)(b * SEQ + q0 + qi * 16 + l15) * DM +
                                  h * HD + ks * 32 + g * 8;
            uint16_t tmp[8], ov[8];
            __builtin_memcpy(tmp, src, 16);
#pragma unroll
            for (int j = 0; j < 8; j++) ov[j] = f2bf(bf2f(tmp[j]) * QSCALE);
            __builtin_memcpy(&qf[qi][ks], ov, 16);
        }

    // accO[qi][nf] holds O^T[d = nf*16 + g*4 + r][q = qi*16 + l15]
    f32x4 accO[2][4];
    const f32x4 z4 = {0.f, 0.f, 0.f, 0.f};
#pragma unroll
    for (int i = 0; i < 2; i++)
#pragma unroll
        for (int j = 0; j < 4; j++) accO[i][j] = z4;
    float m_run[2] = {-1e30f, -1e30f};
    float l_run[2] = {0.f, 0.f};   // per-lane partial (reduced in epilogue)

    // prologue: stage tile 0 into buffer 0
#pragma unroll
    for (int i = 0; i < 2; i++) {
        gll16((const char*)Kb + kglob[i], (char*)Ks[0] + ldsOff[i]);
        gll16((const char*)Vt + vglob[i], (char*)Vs[0] + ldsOff[i]);
    }
    __syncthreads();

    for (int kt = 0; kt < NT; kt++) {
        const int cur = kt & 1;
        if (kt + 1 < NT) {
            const size_t kadv = (size_t)(kt + 1) * (64 * DM * 2);
            const size_t vadv = (size_t)(kt + 1) * (64 * 2);
#pragma unroll
            for (int i = 0; i < 2; i++) {
                gll16((const char*)Kb + kglob[i] + kadv, (char*)Ks[cur ^ 1] + ldsOff[i]);
                gll16((const char*)Vt + vglob[i] + vadv, (char*)Vs[cur ^ 1] + ldsOff[i]);
            }
        }
        const uint16_t* ksrc = Ks[cur];
        const uint16_t* vsrc = Vs[cur];

        // S^T = K . Q^T : sf[kf][qi]; lane holds q=l15(+16qi),
        // permuted-key-row = kf*16 + g*4 + r  (true key = kappa of that)
        f32x4 sf[4][2];
#pragma unroll
        for (int kf = 0; kf < 4; kf++)
#pragma unroll
            for (int qi = 0; qi < 2; qi++) sf[kf][qi] = z4;
        __builtin_amdgcn_s_setprio(1);
#pragma unroll
        for (int ks = 0; ks < 2; ks++)
#pragma unroll
            for (int kf = 0; kf < 4; kf++) {
                const int row = kf * 16 + l15;
                bf16x8 a = *(const bf16x8*)((const char*)ksrc + row * 128 +
                                            ((ks * 64 + g * 16) ^ ((row & 7) << 4)));
#pragma unroll
                for (int qi = 0; qi < 2; qi++)
                    sf[kf][qi] = __builtin_amdgcn_mfma_f32_16x16x32_bf16(
                        a, qf[qi][ks], sf[kf][qi], 0, 0, 0);
            }
        __builtin_amdgcn_s_setprio(0);

        // tile max per q-column (16 values in-lane + 2 shuffles)
        float mx[2];
#pragma unroll
        for (int qi = 0; qi < 2; qi++) {
            float m01 = fmaxf(fmaxf(sf[0][qi][0], sf[0][qi][1]),
                              fmaxf(sf[0][qi][2], sf[0][qi][3]));
            float m23 = fmaxf(fmaxf(sf[1][qi][0], sf[1][qi][1]),
                              fmaxf(sf[1][qi][2], sf[1][qi][3]));
            float m45 = fmaxf(fmaxf(sf[2][qi][0], sf[2][qi][1]),
                              fmaxf(sf[2][qi][2], sf[2][qi][3]));
            float m67 = fmaxf(fmaxf(sf[3][qi][0], sf[3][qi][1]),
                              fmaxf(sf[3][qi][2], sf[3][qi][3]));
            float m = fmaxf(fmaxf(m01, m23), fmaxf(m45, m67));
            m = fmaxf(m, __shfl_xor(m, 16));
            m = fmaxf(m, __shfl_xor(m, 32));
            mx[qi] = m;
        }

        // defer-max: rescale only when max grew past THR (wave-uniform vote)
        const int grew = (mx[0] - m_run[0] > THR) || (mx[1] - m_run[1] > THR);
        if (__any(grew)) {
#pragma unroll
            for (int qi = 0; qi < 2; qi++) {
                const float mnew = fmaxf(m_run[qi], mx[qi]);
                const float corr = EXP2F(m_run[qi] - mnew);
                m_run[qi] = mnew;
                l_run[qi] *= corr;
                // O^T rescale: q = own l15 -> per-lane scalar, no shfl
#pragma unroll
                for (int nf = 0; nf < 4; nf++)
#pragma unroll
                    for (int r = 0; r < 4; r++) accO[qi][nf][r] *= corr;
            }
        }

        // p = exp2(s - m), per-lane partial row-sum
#pragma unroll
        for (int qi = 0; qi < 2; qi++) {
            float ls = 0.f;
#pragma unroll
            for (int kf = 0; kf < 4; kf++)
#pragma unroll
                for (int r = 0; r < 4; r++) {
                    const float p = EXP2F(sf[kf][qi][r] - m_run[qi]);
                    sf[kf][qi][r] = p;
                    ls += p;
                }
            l_run[qi] += ls;
        }

        // P^T B-fragments: pure in-lane repack (kappa ordering makes
        // pa[qi][ks] = {sf[ks][qi][0..3], sf[ks+2][qi][0..3]})
        bf16x8 pa[2][2];
#pragma unroll
        for (int qi = 0; qi < 2; qi++)
#pragma unroll
            for (int ks = 0; ks < 2; ks++) {
                bf16x8 v;
                v[0] = (__bf16)sf[ks][qi][0];
                v[1] = (__bf16)sf[ks][qi][1];
                v[2] = (__bf16)sf[ks][qi][2];
                v[3] = (__bf16)sf[ks][qi][3];
                v[4] = (__bf16)sf[ks + 2][qi][0];
                v[5] = (__bf16)sf[ks + 2][qi][1];
                v[6] = (__bf16)sf[ks + 2][qi][2];
                v[7] = (__bf16)sf[ks + 2][qi][3];
                pa[qi][ks] = v;
            }

        // PV: O^T += V^T . P^T   (A = V^T fragment from LDS, B = pa)
        __builtin_amdgcn_s_setprio(1);
#pragma unroll
        for (int ks = 0; ks < 2; ks++)
#pragma unroll
            for (int nf = 0; nf < 4; nf++) {
                const int row = nf * 16 + l15;   // d-row of V^T
                bf16x8 av = *(const bf16x8*)((const char*)vsrc + row * 128 +
                                             ((ks * 64 + g * 16) ^ ((row & 7) << 4)));
#pragma unroll
                for (int qi = 0; qi < 2; qi++)
                    accO[qi][nf] = __builtin_amdgcn_mfma_f32_16x16x32_bf16(
                        av, pa[qi][ks], accO[qi][nf], 0, 0, 0);
            }
        __builtin_amdgcn_s_setprio(0);

        __syncthreads();   // drains next-tile staging; releases cur buffers
    }

    // epilogue: finish l across the 4 key-groups, then per-lane normalize
#pragma unroll
    for (int qi = 0; qi < 2; qi++) {
        l_run[qi] += __shfl_xor(l_run[qi], 16);
        l_run[qi] += __shfl_xor(l_run[qi], 32);
        l_run[qi] = 1.f / l_run[qi];
    }

    // O^T -> LDS bounce (reuse Ks area: 4 waves x 4 KiB) -> coalesced store
    uint16_t* bw = &Ks[0][0] + wave * 2048;   // 4 KiB per wave
#pragma unroll
    for (int qi = 0; qi < 2; qi++) {
        const int q = qi * 16 + l15;
        const int swz = (q & 7) << 4;
#pragma unroll
        for (int nf = 0; nf < 4; nf++) {
            bf16x4 ov;
            ov[0] = (__bf16)(accO[qi][nf][0] * l_run[qi]);
            ov[1] = (__bf16)(accO[qi][nf][1] * l_run[qi]);
            ov[2] = (__bf16)(accO[qi][nf][2] * l_run[qi]);
            ov[3] = (__bf16)(accO[qi][nf][3] * l_run[qi]);
            const int off = (q * 128 + nf * 32 + g * 8) ^ swz;
            __builtin_memcpy((char*)bw + off, &ov, 8);
        }
    }
    __syncthreads();
    {
        const int q = lane >> 1, part = lane & 1;
        const int swz = (q & 7) << 4;
        const size_t orow = ((size_t)(b * SEQ + q0 + q) * DM) + h * HD + part * 32;
#pragma unroll
        for (int t = 0; t < 4; t++) {
            bf16x8 ov;
            __builtin_memcpy(&ov, (const char*)bw + ((q * 128 + part * 64 + t * 16) ^ swz),
                             16);
            __builtin_memcpy(&AO[orow + t * 8], &ov, 16);
        }
    }
}

// ---------------------------------------------------------------------------
extern "C" void kernel_launch(void* const* d_in, const int* in_sizes, int n_in,
                              void* d_out, int out_size, void* d_ws, size_t ws_size,
                              hipStream_t stream) {
    const float* xq = (const float*)d_in[0];
    const float* xk = (const float*)d_in[1];
    const float* xv = (const float*)d_in[2];
    const float* wq = (const float*)d_in[3];
    const float* wk = (const float*)d_in[4];
    const float* wv = (const float*)d_in[5];
    const float* wo = (const float*)d_in[6];
    float* out = (float*)d_out;
    uint16_t* ws = (uint16_t*)d_ws;

    const size_t SZ = (size_t)NB * SEQ * DM;   // 8.39M elems
    const size_t WSZ = (size_t)DM * DM;        // 1.05M elems
    uint16_t* bufA = ws;            // converted input (reused), then VT
    uint16_t* Qb = ws + SZ;
    uint16_t* Kbuf = ws + 2 * SZ;
    uint16_t* Vb = ws + 3 * SZ;     // V, then AO
    uint16_t* WqT = ws + 4 * SZ;
    uint16_t* WkT = WqT + WSZ;
    uint16_t* WvT = WkT + WSZ;
    uint16_t* WoT = WvT + WSZ;

    const dim3 tb(32, 8);
    transpose_cvt<<<dim3(32, 32, 1), tb, 0, stream>>>(wq, WqT, DM, DM);
    transpose_cvt<<<dim3(32, 32, 1), tb, 0, stream>>>(wk, WkT, DM, DM);
    transpose_cvt<<<dim3(32, 32, 1), tb, 0, stream>>>(wv, WvT, DM, DM);
    transpose_cvt<<<dim3(32, 32, 1), tb, 0, stream>>>(wo, WoT, DM, DM);

    const int cvtBlocks = (int)(SZ / (256 * 8));   // 4096
    const dim3 gg(DM / 128, NB * SEQ / 128);

    cvt_f32_bf16<<<cvtBlocks, 256, 0, stream>>>(xq, bufA);
    gemm_bf16<uint16_t><<<gg, 256, 0, stream>>>(bufA, WqT, Qb, NB * SEQ, DM, DM);

    cvt_f32_bf16<<<cvtBlocks, 256, 0, stream>>>(xk, bufA);
    gemm_bf16<uint16_t><<<gg, 256, 0, stream>>>(bufA, WkT, Kbuf, NB * SEQ, DM, DM);

    cvt_f32_bf16<<<cvtBlocks, 256, 0, stream>>>(xv, bufA);
    gemm_bf16<uint16_t><<<gg, 256, 0, stream>>>(bufA, WvT, Vb, NB * SEQ, DM, DM);

    // V^T: bufA now holds Vt[b][dglob][s]
    transpose_bf16<<<dim3(DM / 32, SEQ / 32, NB), tb, 0, stream>>>(Vb, bufA, SEQ, DM);

    // attention: reads Qb, Kbuf, bufA(VT); writes Vb (as AO)
    attn_fwd<<<dim3(SEQ / 128, NH, NB), 256, 0, stream>>>(Qb, Kbuf, bufA, Vb);

    // output projection: f32 store
    gemm_bf16<float><<<gg, 256, 0, stream>>>(Vb, WoT, out, NB * SEQ, DM, DM);
}